// Round 1
// baseline (413.875 us; speedup 1.0000x reference)
//
#include <hip/hip_runtime.h>

#define B_ 16
#define N_ 512
#define D_ 64
#define K_ 8
#define TI 2   // rows of i per block (one wave)

// Bucket accumulate with wave-uniform k (scalar branch tree, 1 v_add per edge).
#define ACCUM(kv, bucket) switch (kv) { \
    case 1: (bucket)[0] += v_; break; case 2: (bucket)[1] += v_; break; \
    case 3: (bucket)[2] += v_; break; case 4: (bucket)[3] += v_; break; \
    case 5: (bucket)[4] += v_; break; case 6: (bucket)[5] += v_; break; \
    case 7: (bucket)[6] += v_; break; case 8: (bucket)[7] += v_; break; \
    default: break; }

__global__ __launch_bounds__(64) void ggnn_msg(
    const float* __restrict__ h,      // [B,N,D]
    const int*   __restrict__ adj,    // [B,N,N] in [0,K]
    const float* __restrict__ Min,    // [K,D,D]
    const float* __restrict__ Mout,   // [K,D,D]
    const float* __restrict__ bias,   // [2D]
    float* __restrict__ out) {        // [B,N,2D]
  const int blk = blockIdx.x;
  const int b  = blk / (N_ / TI);
  const int i0 = (blk % (N_ / TI)) * TI;
  const int d  = threadIdx.x;  // 0..63 = output/feature dim

  float s_in[TI][K_], s_out[TI][K_];
#pragma unroll
  for (int r = 0; r < TI; ++r)
#pragma unroll
    for (int k = 0; k < K_; ++k) { s_in[r][k] = 0.f; s_out[r][k] = 0.f; }

  const int*   rowp0 = adj + (b * N_ + i0) * N_;      // adj[b, i0,   :]
  const int*   rowp1 = rowp0 + N_;                    // adj[b, i0+1, :]
  const int*   colp  = adj + b * N_ * N_ + i0;        // adj[b, j, i0 + r] at colp[j*N_ + r]
  const float* hb    = h + b * N_ * D_ + d;

  for (int j0 = 0; j0 < N_; j0 += 8) {
    float hv[8];
    int kr0[8], kr1[8], kc0[8], kc1[8];
#pragma unroll
    for (int m = 0; m < 8; ++m) {
      hv[m]  = hb[(j0 + m) * D_];          // coalesced 256B/wave
      kr0[m] = rowp0[j0 + m];              // uniform -> s_load
      kr1[m] = rowp1[j0 + m];
      kc0[m] = colp[(j0 + m) * N_];        // uniform strided -> s_load
      kc1[m] = colp[(j0 + m) * N_ + 1];
    }
#pragma unroll
    for (int m = 0; m < 8; ++m) {
      const float v_ = hv[m];
      ACCUM(kr0[m], s_in[0]);
      ACCUM(kr1[m], s_in[1]);
      ACCUM(kc0[m], s_out[0]);
      ACCUM(kc1[m], s_out[1]);
    }
  }

  // Stage 2: a[d] = bias[d] + sum_{k,e} M[k][d][e] * S[k][e]
  __shared__ float S[TI][2][K_][D_];   // 8 KB
#pragma unroll
  for (int r = 0; r < TI; ++r)
#pragma unroll
    for (int k = 0; k < K_; ++k) {
      S[r][0][k][d] = s_in[r][k];
      S[r][1][k][d] = s_out[r][k];
    }
  __syncthreads();

  float acc_in[TI], acc_out[TI];
#pragma unroll
  for (int r = 0; r < TI; ++r) { acc_in[r] = bias[d]; acc_out[r] = bias[D_ + d]; }

  for (int k = 0; k < K_; ++k) {
#pragma unroll
    for (int e0 = 0; e0 < D_; e0 += 4) {
      const float4 mi = *(const float4*)(Min  + (k * D_ + d) * D_ + e0);
      const float4 mo = *(const float4*)(Mout + (k * D_ + d) * D_ + e0);
#pragma unroll
      for (int r = 0; r < TI; ++r) {
        const float4 si = *(const float4*)(&S[r][0][k][e0]);  // broadcast
        const float4 so = *(const float4*)(&S[r][1][k][e0]);
        acc_in[r]  += mi.x * si.x + mi.y * si.y + mi.z * si.z + mi.w * si.w;
        acc_out[r] += mo.x * so.x + mo.y * so.y + mo.z * so.z + mo.w * so.w;
      }
    }
  }

#pragma unroll
  for (int r = 0; r < TI; ++r) {
    out[(b * N_ + i0 + r) * (2 * D_) + d]       = acc_in[r];
    out[(b * N_ + i0 + r) * (2 * D_) + D_ + d]  = acc_out[r];
  }
}

extern "C" void kernel_launch(void* const* d_in, const int* in_sizes, int n_in,
                              void* d_out, int out_size, void* d_ws, size_t ws_size,
                              hipStream_t stream) {
  const float* h    = (const float*)d_in[0];  // node_states [B,N,D]
  const int*   adj  = (const int*)d_in[1];    // adjacency_in [B,N,N]
  // d_in[2] = distance, unused
  const float* Min  = (const float*)d_in[3];  // matrices_in [K,D,D]
  const float* Mout = (const float*)d_in[4];  // matrices_out [K,D,D]
  const float* bias = (const float*)d_in[5];  // message_bias [2D]
  float* out = (float*)d_out;

  dim3 grid(B_ * N_ / TI);
  dim3 block(64);
  hipLaunchKernelGGL(ggnn_msg, grid, block, 0, stream, h, adj, Min, Mout, bias, out);
}

// Round 2
// 391.565 us; speedup vs baseline: 1.0570x; 1.0570x over previous
//
#include <hip/hip_runtime.h>

#define B_ 16
#define N_ 512
#define D_ 64
#define K_ 8
#define TI 2   // rows of i per block (one wave)

// Bucket accumulate with wave-uniform k forced into SGPR (scalar branch tree,
// 1 v_add per edge). kv MUST be the result of readfirstlane.
#define ACCUM(kv, bucket) switch (kv) { \
    case 1: (bucket)[0] += v_; break; case 2: (bucket)[1] += v_; break; \
    case 3: (bucket)[2] += v_; break; case 4: (bucket)[3] += v_; break; \
    case 5: (bucket)[4] += v_; break; case 6: (bucket)[5] += v_; break; \
    case 7: (bucket)[6] += v_; break; case 8: (bucket)[7] += v_; break; \
    default: break; }

__global__ __launch_bounds__(64) void ggnn_msg(
    const float* __restrict__ h,      // [B,N,D]
    const int*   __restrict__ adj,    // [B,N,N] in [0,K]
    const float* __restrict__ Min,    // [K,D,D]
    const float* __restrict__ Mout,   // [K,D,D]
    const float* __restrict__ bias,   // [2D]
    float* __restrict__ out) {        // [B,N,2D]
  const int blk = blockIdx.x;
  const int b  = blk / (N_ / TI);
  const int i0 = (blk % (N_ / TI)) * TI;
  const int d  = threadIdx.x;  // 0..63 = output/feature dim

  float s_in[TI][K_], s_out[TI][K_];
#pragma unroll
  for (int r = 0; r < TI; ++r)
#pragma unroll
    for (int k = 0; k < K_; ++k) { s_in[r][k] = 0.f; s_out[r][k] = 0.f; }

  const int*   rowp0 = adj + (b * N_ + i0) * N_;      // adj[b, i0,   :]
  const int*   rowp1 = rowp0 + N_;                    // adj[b, i0+1, :]
  const int*   colp  = adj + b * N_ * N_ + i0;        // adj[b, j, i0 + r] at colp[j*N_ + r]
  const float* hb    = h + b * N_ * D_ + d;

  for (int j0 = 0; j0 < N_; j0 += 8) {
    float hv[8];
    int kr0[8], kr1[8], kc0[8], kc1[8];
#pragma unroll
    for (int m = 0; m < 8; ++m) {
      hv[m]  = hb[(j0 + m) * D_];          // coalesced 256B/wave
      kr0[m] = rowp0[j0 + m];              // wave-uniform
      kr1[m] = rowp1[j0 + m];
      kc0[m] = colp[(j0 + m) * N_];        // wave-uniform strided
      kc1[m] = colp[(j0 + m) * N_ + 1];
    }
#pragma unroll
    for (int m = 0; m < 8; ++m) {
      const float v_ = hv[m];
      // Force the edge types into SGPRs so the switch is a SCALAR branch
      // tree (s_cmp/s_cbranch) instead of a divergent exec-mask cascade.
      const int k_r0 = __builtin_amdgcn_readfirstlane(kr0[m]);
      const int k_r1 = __builtin_amdgcn_readfirstlane(kr1[m]);
      const int k_c0 = __builtin_amdgcn_readfirstlane(kc0[m]);
      const int k_c1 = __builtin_amdgcn_readfirstlane(kc1[m]);
      ACCUM(k_r0, s_in[0]);
      ACCUM(k_r1, s_in[1]);
      ACCUM(k_c0, s_out[0]);
      ACCUM(k_c1, s_out[1]);
    }
  }

  // Stage 2: a[d] = bias[d] + sum_{k,e} M[k][d][e] * S[k][e]
  __shared__ float S[TI][2][K_][D_];   // 8 KB
#pragma unroll
  for (int r = 0; r < TI; ++r)
#pragma unroll
    for (int k = 0; k < K_; ++k) {
      S[r][0][k][d] = s_in[r][k];
      S[r][1][k][d] = s_out[r][k];
    }
  __syncthreads();

  float acc_in[TI], acc_out[TI];
#pragma unroll
  for (int r = 0; r < TI; ++r) { acc_in[r] = bias[d]; acc_out[r] = bias[D_ + d]; }

  for (int k = 0; k < K_; ++k) {
#pragma unroll
    for (int e0 = 0; e0 < D_; e0 += 4) {
      const float4 mi = *(const float4*)(Min  + (k * D_ + d) * D_ + e0);
      const float4 mo = *(const float4*)(Mout + (k * D_ + d) * D_ + e0);
#pragma unroll
      for (int r = 0; r < TI; ++r) {
        const float4 si = *(const float4*)(&S[r][0][k][e0]);  // broadcast
        const float4 so = *(const float4*)(&S[r][1][k][e0]);
        acc_in[r]  += mi.x * si.x + mi.y * si.y + mi.z * si.z + mi.w * si.w;
        acc_out[r] += mo.x * so.x + mo.y * so.y + mo.z * so.z + mo.w * so.w;
      }
    }
  }

#pragma unroll
  for (int r = 0; r < TI; ++r) {
    out[(b * N_ + i0 + r) * (2 * D_) + d]       = acc_in[r];
    out[(b * N_ + i0 + r) * (2 * D_) + D_ + d]  = acc_out[r];
  }
}

extern "C" void kernel_launch(void* const* d_in, const int* in_sizes, int n_in,
                              void* d_out, int out_size, void* d_ws, size_t ws_size,
                              hipStream_t stream) {
  const float* h    = (const float*)d_in[0];  // node_states [B,N,D]
  const int*   adj  = (const int*)d_in[1];    // adjacency_in [B,N,N]
  // d_in[2] = distance, unused
  const float* Min  = (const float*)d_in[3];  // matrices_in [K,D,D]
  const float* Mout = (const float*)d_in[4];  // matrices_out [K,D,D]
  const float* bias = (const float*)d_in[5];  // message_bias [2D]
  float* out = (float*)d_out;

  dim3 grid(B_ * N_ / TI);
  dim3 block(64);
  hipLaunchKernelGGL(ggnn_msg, grid, block, 0, stream, h, adj, Min, Mout, bias, out);
}

// Round 3
// 262.027 us; speedup vs baseline: 1.5795x; 1.4944x over previous
//
#include <hip/hip_runtime.h>

#define B_ 16
#define N_ 512
#define D_ 64
#define K_ 8

// ---------------- ws layout ----------------
// ws2 : [B][N][N] int2  (pre-scaled byte offsets {k_in*256, k_out*256})  33,554,432 B
// Tin : [B][N][K+1][D] float                                            18,874,368 B
// Tout: [B][N][K+1][D] float                                            18,874,368 B
#define WS2_BYTES ((size_t)B_ * N_ * N_ * 8)
#define T_BYTES   ((size_t)B_ * N_ * (K_ + 1) * D_ * 4)
#define TROW 2304  // (K+1)*D*4 bytes per j

// ---------- kernel A: transpose + pre-scale + interleave adjacency ----------
__global__ __launch_bounds__(256) void prep_adj(const int* __restrict__ adj,
                                                int2* __restrict__ ws2) {
  __shared__ int ta[64][65];
  __shared__ int tb[64][65];
  const int blk = blockIdx.x;          // 16 b * 8 it * 8 jt = 1024
  const int b  = blk >> 6;
  const int it = (blk >> 3) & 7;
  const int jt = blk & 7;
  const int i0 = it * 64, j0 = jt * 64;
  const int lane = threadIdx.x & 63, w = threadIdx.x >> 6;
  const int* ab = adj + (size_t)b * N_ * N_;
#pragma unroll
  for (int r = w; r < 64; r += 4) {
    ta[r][lane] = ab[(size_t)(i0 + r) * N_ + j0 + lane];   // in-tile, coalesced
    tb[r][lane] = ab[(size_t)(j0 + r) * N_ + i0 + lane];   // out-tile, coalesced
  }
  __syncthreads();
  int2* wb = ws2 + (size_t)b * N_ * N_;
#pragma unroll
  for (int r = w; r < 64; r += 4) {
    int2 v;
    v.x = ta[r][lane] << 8;      // k_in  * 256 bytes (k*64 floats)
    v.y = tb[lane][r] << 8;      // k_out * 256 bytes (transposed read, 2-way bank ok)
    wb[(size_t)(i0 + r) * N_ + j0 + lane] = v;
  }
}

// ---------- kernel B: T[b,j,k,:] = M[k] @ h[b,j,:], zero slot k=0 ----------
__global__ __launch_bounds__(256) void build_T(const float* __restrict__ h,
                                               const float* __restrict__ Min,
                                               const float* __restrict__ Mout,
                                               float* __restrict__ Tin,
                                               float* __restrict__ Tout) {
  // grid 1024 = (k1:8) x (dir:2) x (b:16) x (q:4); wave handles 32 j's
  const int blk = blockIdx.x;
  const int q   = blk & 3;
  const int b   = (blk >> 2) & 15;
  const int dir = (blk >> 6) & 1;
  const int k1  = (blk >> 7) & 7;            // matrix index 0..7 -> slot k1+1
  const int lane = threadIdx.x & 63, w = threadIdx.x >> 6;

  const float* Mrow = (dir ? Mout : Min) + ((size_t)k1 * D_ + lane) * D_;
  float m[64];
#pragma unroll
  for (int e = 0; e < 64; e += 4) {
    const float4 t = *(const float4*)(Mrow + e);
    m[e] = t.x; m[e + 1] = t.y; m[e + 2] = t.z; m[e + 3] = t.w;
  }
  const int jbase = q * 128 + w * 32;
  const float* hb = h + (size_t)b * N_ * D_;
  float* Tb = (dir ? Tout : Tin) + (size_t)b * N_ * (K_ + 1) * D_ + (size_t)(k1 + 1) * D_ + lane;

  for (int jj = 0; jj < 32; ++jj) {
    const int j = jbase + jj;
    const float* hr = hb + (size_t)j * D_;   // wave-uniform -> s_load
    float a0 = 0.f, a1 = 0.f, a2 = 0.f, a3 = 0.f;
#pragma unroll
    for (int e = 0; e < 64; e += 4) {
      a0 += m[e]     * hr[e];
      a1 += m[e + 1] * hr[e + 1];
      a2 += m[e + 2] * hr[e + 2];
      a3 += m[e + 3] * hr[e + 3];
    }
    Tb[(size_t)j * (K_ + 1) * D_] = (a0 + a1) + (a2 + a3);
  }
  if (k1 == 0 && dir == 0) {  // zero slot k=0, both directions, this j-range
    float* z1 = Tin  + (size_t)b * N_ * (K_ + 1) * D_ + lane;
    float* z2 = Tout + (size_t)b * N_ * (K_ + 1) * D_ + lane;
    for (int jj = 0; jj < 32; ++jj) {
      const size_t o = (size_t)(jbase + jj) * (K_ + 1) * D_;
      z1[o] = 0.f;
      z2[o] = 0.f;
    }
  }
}

// ---------- kernel C: branch-free edge gather ----------
__global__ __launch_bounds__(256) void gather_msg(const int2* __restrict__ ws2,
                                                  const float* __restrict__ Tin,
                                                  const float* __restrict__ Tout,
                                                  const float* __restrict__ bias,
                                                  float* __restrict__ out) {
  __shared__ int2 rows[4][N_];   // 16 KB
  const int blk = blockIdx.x;    // 2048 = b*128 + g
  const int b = blk >> 7, g = blk & 127;
  const int lane = threadIdx.x & 63, w = threadIdx.x >> 6;
  const int i = g * 4 + w;

  // stage this wave's interleaved edge-type row (4 KB, coalesced int4)
  const int4* r4 = (const int4*)(ws2 + ((size_t)b * N_ + i) * N_);
  int4* l4 = (int4*)&rows[w][0];
#pragma unroll
  for (int t = 0; t < 4; ++t) l4[lane + 64 * t] = r4[lane + 64 * t];
  __syncthreads();

  const char* tin  = (const char*)(Tin  + (size_t)b * N_ * (K_ + 1) * D_);
  const char* tout = (const char*)(Tout + (size_t)b * N_ * (K_ + 1) * D_);
  const unsigned d4 = lane * 4;
  float accI = 0.f, accO = 0.f;
#pragma unroll 8
  for (int j = 0; j < N_; ++j) {
    const int2 kk = rows[w][j];               // broadcast ds_read_b64
    const unsigned base = (unsigned)j * TROW + d4;
    accI += *(const float*)(tin  + (base + (unsigned)kk.x));
    accO += *(const float*)(tout + (base + (unsigned)kk.y));
  }
  float* o = out + ((size_t)b * N_ + i) * (2 * D_);
  o[lane]      = accI + bias[lane];
  o[D_ + lane] = accO + bias[D_ + lane];
}

// ---------- fallback (round-1 kernel) if ws is too small ----------
#define ACCUM(kv, bucket) switch (kv) { \
    case 1: (bucket)[0] += v_; break; case 2: (bucket)[1] += v_; break; \
    case 3: (bucket)[2] += v_; break; case 4: (bucket)[3] += v_; break; \
    case 5: (bucket)[4] += v_; break; case 6: (bucket)[5] += v_; break; \
    case 7: (bucket)[6] += v_; break; case 8: (bucket)[7] += v_; break; \
    default: break; }

__global__ __launch_bounds__(64) void ggnn_fallback(
    const float* __restrict__ h, const int* __restrict__ adj,
    const float* __restrict__ Min, const float* __restrict__ Mout,
    const float* __restrict__ bias, float* __restrict__ out) {
  const int blk = blockIdx.x;
  const int b  = blk / (N_ / 2);
  const int i0 = (blk % (N_ / 2)) * 2;
  const int d  = threadIdx.x;
  float s_in[2][K_], s_out[2][K_];
#pragma unroll
  for (int r = 0; r < 2; ++r)
#pragma unroll
    for (int k = 0; k < K_; ++k) { s_in[r][k] = 0.f; s_out[r][k] = 0.f; }
  const int* rowp0 = adj + (b * N_ + i0) * N_;
  const int* rowp1 = rowp0 + N_;
  const int* colp  = adj + b * N_ * N_ + i0;
  const float* hb  = h + b * N_ * D_ + d;
  for (int j0 = 0; j0 < N_; j0 += 8) {
    float hv[8]; int kr0[8], kr1[8], kc0[8], kc1[8];
#pragma unroll
    for (int m = 0; m < 8; ++m) {
      hv[m] = hb[(j0 + m) * D_];
      kr0[m] = rowp0[j0 + m]; kr1[m] = rowp1[j0 + m];
      kc0[m] = colp[(j0 + m) * N_]; kc1[m] = colp[(j0 + m) * N_ + 1];
    }
#pragma unroll
    for (int m = 0; m < 8; ++m) {
      const float v_ = hv[m];
      ACCUM(kr0[m], s_in[0]); ACCUM(kr1[m], s_in[1]);
      ACCUM(kc0[m], s_out[0]); ACCUM(kc1[m], s_out[1]);
    }
  }
  __shared__ float S[2][2][K_][D_];
#pragma unroll
  for (int r = 0; r < 2; ++r)
#pragma unroll
    for (int k = 0; k < K_; ++k) { S[r][0][k][d] = s_in[r][k]; S[r][1][k][d] = s_out[r][k]; }
  __syncthreads();
  float acc_in[2], acc_out[2];
#pragma unroll
  for (int r = 0; r < 2; ++r) { acc_in[r] = bias[d]; acc_out[r] = bias[D_ + d]; }
  for (int k = 0; k < K_; ++k) {
#pragma unroll
    for (int e0 = 0; e0 < D_; e0 += 4) {
      const float4 mi = *(const float4*)(Min  + (k * D_ + d) * D_ + e0);
      const float4 mo = *(const float4*)(Mout + (k * D_ + d) * D_ + e0);
#pragma unroll
      for (int r = 0; r < 2; ++r) {
        const float4 si = *(const float4*)(&S[r][0][k][e0]);
        const float4 so = *(const float4*)(&S[r][1][k][e0]);
        acc_in[r]  += mi.x * si.x + mi.y * si.y + mi.z * si.z + mi.w * si.w;
        acc_out[r] += mo.x * so.x + mo.y * so.y + mo.z * so.z + mo.w * so.w;
      }
    }
  }
#pragma unroll
  for (int r = 0; r < 2; ++r) {
    out[(b * N_ + i0 + r) * (2 * D_) + d]      = acc_in[r];
    out[(b * N_ + i0 + r) * (2 * D_) + D_ + d] = acc_out[r];
  }
}

extern "C" void kernel_launch(void* const* d_in, const int* in_sizes, int n_in,
                              void* d_out, int out_size, void* d_ws, size_t ws_size,
                              hipStream_t stream) {
  const float* h    = (const float*)d_in[0];
  const int*   adj  = (const int*)d_in[1];
  const float* Min  = (const float*)d_in[3];
  const float* Mout = (const float*)d_in[4];
  const float* bias = (const float*)d_in[5];
  float* out = (float*)d_out;

  if (ws_size < WS2_BYTES + 2 * T_BYTES) {
    hipLaunchKernelGGL(ggnn_fallback, dim3(B_ * N_ / 2), dim3(64), 0, stream,
                       h, adj, Min, Mout, bias, out);
    return;
  }
  int2*  ws2  = (int2*)d_ws;
  float* Tin  = (float*)((char*)d_ws + WS2_BYTES);
  float* Tout = (float*)((char*)d_ws + WS2_BYTES + T_BYTES);

  hipLaunchKernelGGL(prep_adj, dim3(1024), dim3(256), 0, stream, adj, ws2);
  hipLaunchKernelGGL(build_T,  dim3(1024), dim3(256), 0, stream, h, Min, Mout, Tin, Tout);
  hipLaunchKernelGGL(gather_msg, dim3(2048), dim3(256), 0, stream, ws2, Tin, Tout, bias, out);
}

// Round 4
// 228.698 us; speedup vs baseline: 1.8097x; 1.1457x over previous
//
#include <hip/hip_runtime.h>
#include <hip/hip_bf16.h>

#define B_ 16
#define N_ 512
#define D_ 64
#define K_ 8

// ---------------- ws layout ----------------
// wsu : [B][N][N] ushort {kin | kout<<8}    8,388,608 B
// Tin : [B][N][K+1][D] bf16                 9,437,184 B
// Tout: [B][N][K+1][D] bf16                 9,437,184 B
#define WSU_BYTES ((size_t)B_ * N_ * N_ * 2)
#define T_BYTES   ((size_t)B_ * N_ * (K_ + 1) * D_ * 2)
#define TROWB 1152  // (K+1)*D*2 bytes per j row

// ---------- kernel A: transpose + pack edge types (ushort per edge) ----------
__global__ __launch_bounds__(256) void prep_adj(const int* __restrict__ adj,
                                                unsigned short* __restrict__ wsu) {
  __shared__ int ta[64][65];
  __shared__ int tb[64][65];
  const int blk = blockIdx.x;          // 1024
  const int xcd = blk & 7, rest = blk >> 3;
  const int b = xcd + 8 * (rest & 1);  // batch b -> XCD b%8
  const int tile = rest >> 1;          // 0..63
  const int i0 = (tile >> 3) * 64, j0 = (tile & 7) * 64;
  const int lane = threadIdx.x & 63, w = threadIdx.x >> 6;
  const int* ab = adj + (size_t)b * N_ * N_;
#pragma unroll
  for (int r = w; r < 64; r += 4) {
    ta[r][lane] = ab[(size_t)(i0 + r) * N_ + j0 + lane];   // in-tile
    tb[r][lane] = ab[(size_t)(j0 + r) * N_ + i0 + lane];   // out-tile (to transpose)
  }
  __syncthreads();
  unsigned short* wb = wsu + (size_t)b * N_ * N_;
#pragma unroll
  for (int r = w; r < 64; r += 4) {
    wb[(size_t)(i0 + r) * N_ + j0 + lane] =
        (unsigned short)(ta[r][lane] | (tb[lane][r] << 8));
  }
}

// ---------- kernel B: T[b,j,k,:] = M[k] @ h[b,j,:] (bf16), zero slot k=0 ----------
__global__ __launch_bounds__(256) void build_T(const float* __restrict__ h,
                                               const float* __restrict__ Min,
                                               const float* __restrict__ Mout,
                                               __hip_bfloat16* __restrict__ Tin,
                                               __hip_bfloat16* __restrict__ Tout) {
  const int blk = blockIdx.x;          // 1024
  const int xcd = blk & 7, rest = blk >> 3;
  const int b = xcd + 8 * (rest & 1);
  const int u = rest >> 1;             // 0..63
  const int k1 = u & 7, dir = (u >> 3) & 1, q = u >> 4;   // q 0..3
  const int lane = threadIdx.x & 63, w = threadIdx.x >> 6;

  const float* Mrow = (dir ? Mout : Min) + ((size_t)k1 * D_ + lane) * D_;
  float m[64];
#pragma unroll
  for (int e = 0; e < 64; e += 4) {
    const float4 t = *(const float4*)(Mrow + e);
    m[e] = t.x; m[e + 1] = t.y; m[e + 2] = t.z; m[e + 3] = t.w;
  }
  const int jbase = q * 128 + w * 32;
  const float* hb = h + (size_t)b * N_ * D_;
  __hip_bfloat16* Tb = (dir ? Tout : Tin) + (size_t)b * N_ * (K_ + 1) * D_ +
                       (size_t)(k1 + 1) * D_ + lane;

  for (int jj = 0; jj < 32; ++jj) {
    const int j = jbase + jj;
    const float* hr = hb + (size_t)j * D_;   // wave-uniform -> scalar loads
    float a0 = 0.f, a1 = 0.f, a2 = 0.f, a3 = 0.f;
#pragma unroll
    for (int e = 0; e < 64; e += 4) {
      a0 += m[e]     * hr[e];
      a1 += m[e + 1] * hr[e + 1];
      a2 += m[e + 2] * hr[e + 2];
      a3 += m[e + 3] * hr[e + 3];
    }
    Tb[(size_t)j * (K_ + 1) * D_] = __float2bfloat16((a0 + a1) + (a2 + a3));
  }
  if (k1 == 0 && dir == 0) {  // zero slot k=0 in both arrays for this j range
    __hip_bfloat16 z = __float2bfloat16(0.f);
    __hip_bfloat16* z1 = Tin  + (size_t)b * N_ * (K_ + 1) * D_ + lane;
    __hip_bfloat16* z2 = Tout + (size_t)b * N_ * (K_ + 1) * D_ + lane;
    for (int jj = 0; jj < 32; ++jj) {
      const size_t o = (size_t)(jbase + jj) * (K_ + 1) * D_;
      z1[o] = z;
      z2[o] = z;
    }
  }
}

// ---------- kernel C: branch-free edge gather (2 rows/wave, 2 d's/lane) ----------
__global__ __launch_bounds__(256) void gather_msg(
    const unsigned short* __restrict__ wsu,
    const __hip_bfloat16* __restrict__ Tin,
    const __hip_bfloat16* __restrict__ Tout,
    const float* __restrict__ bias,
    float* __restrict__ out) {
  __shared__ int4 ed4[512];            // = ushort ed[8][512], 8 KB
  const int blk = blockIdx.x;          // 1024
  const int xcd = blk & 7, rest = blk >> 3;
  const int b = xcd + 8 * (rest & 1);
  const int i0 = (rest >> 1) * 8;      // 8 rows per block
  const int tid = threadIdx.x;
  const int w = tid >> 6, lane = tid & 63;
  const int half = lane >> 5, lane5 = lane & 31;

  const int4* src = (const int4*)(wsu + ((size_t)b * N_ + i0) * N_);
  ed4[tid]       = src[tid];
  ed4[tid + 256] = src[tid + 256];
  __syncthreads();

  const unsigned short* edrow =
      (const unsigned short*)ed4 + (2 * w + half) * N_;  // this lane's row

  const char* tinb  = (const char*)Tin  + (size_t)b * N_ * TROWB;
  const char* toutb = (const char*)Tout + (size_t)b * N_ * TROWB;
  unsigned voff = (unsigned)lane5 * 4;   // byte offset of d-pair within 128B k-row
  float aI0 = 0.f, aI1 = 0.f, aO0 = 0.f, aO1 = 0.f;
#pragma unroll 8
  for (int j = 0; j < N_; ++j) {
    const unsigned v = edrow[j];
    const unsigned ui = *(const unsigned*)(tinb  + (voff + ((v & 0xFFu) << 7)));
    const unsigned uo = *(const unsigned*)(toutb + (voff + ((v >> 8) << 7)));
    aI0 += __uint_as_float(ui << 16);
    aI1 += __uint_as_float(ui & 0xFFFF0000u);
    aO0 += __uint_as_float(uo << 16);
    aO1 += __uint_as_float(uo & 0xFFFF0000u);
    voff += TROWB;
  }

  const int row = i0 + 2 * w + half;
  const int d = lane5 * 2;
  float* orow = out + ((size_t)b * N_ + row) * (2 * D_);
  const float2 bi = *(const float2*)(bias + d);
  const float2 bo = *(const float2*)(bias + D_ + d);
  *(float2*)(orow + d)      = make_float2(aI0 + bi.x, aI1 + bi.y);
  *(float2*)(orow + D_ + d) = make_float2(aO0 + bo.x, aO1 + bo.y);
}

// ---------- fallback (branch-tree kernel) if ws is too small ----------
#define ACCUM(kv, bucket) switch (kv) { \
    case 1: (bucket)[0] += v_; break; case 2: (bucket)[1] += v_; break; \
    case 3: (bucket)[2] += v_; break; case 4: (bucket)[3] += v_; break; \
    case 5: (bucket)[4] += v_; break; case 6: (bucket)[5] += v_; break; \
    case 7: (bucket)[6] += v_; break; case 8: (bucket)[7] += v_; break; \
    default: break; }

__global__ __launch_bounds__(64) void ggnn_fallback(
    const float* __restrict__ h, const int* __restrict__ adj,
    const float* __restrict__ Min, const float* __restrict__ Mout,
    const float* __restrict__ bias, float* __restrict__ out) {
  const int blk = blockIdx.x;
  const int b  = blk / (N_ / 2);
  const int i0 = (blk % (N_ / 2)) * 2;
  const int d  = threadIdx.x;
  float s_in[2][K_], s_out[2][K_];
#pragma unroll
  for (int r = 0; r < 2; ++r)
#pragma unroll
    for (int k = 0; k < K_; ++k) { s_in[r][k] = 0.f; s_out[r][k] = 0.f; }
  const int* rowp0 = adj + (b * N_ + i0) * N_;
  const int* rowp1 = rowp0 + N_;
  const int* colp  = adj + b * N_ * N_ + i0;
  const float* hb  = h + b * N_ * D_ + d;
  for (int j0 = 0; j0 < N_; j0 += 8) {
    float hv[8]; int kr0[8], kr1[8], kc0[8], kc1[8];
#pragma unroll
    for (int m = 0; m < 8; ++m) {
      hv[m] = hb[(j0 + m) * D_];
      kr0[m] = rowp0[j0 + m]; kr1[m] = rowp1[j0 + m];
      kc0[m] = colp[(j0 + m) * N_]; kc1[m] = colp[(j0 + m) * N_ + 1];
    }
#pragma unroll
    for (int m = 0; m < 8; ++m) {
      const float v_ = hv[m];
      ACCUM(kr0[m], s_in[0]); ACCUM(kr1[m], s_in[1]);
      ACCUM(kc0[m], s_out[0]); ACCUM(kc1[m], s_out[1]);
    }
  }
  __shared__ float S[2][2][K_][D_];
#pragma unroll
  for (int r = 0; r < 2; ++r)
#pragma unroll
    for (int k = 0; k < K_; ++k) { S[r][0][k][d] = s_in[r][k]; S[r][1][k][d] = s_out[r][k]; }
  __syncthreads();
  float acc_in[2], acc_out[2];
#pragma unroll
  for (int r = 0; r < 2; ++r) { acc_in[r] = bias[d]; acc_out[r] = bias[D_ + d]; }
  for (int k = 0; k < K_; ++k) {
#pragma unroll
    for (int e0 = 0; e0 < D_; e0 += 4) {
      const float4 mi = *(const float4*)(Min  + (k * D_ + d) * D_ + e0);
      const float4 mo = *(const float4*)(Mout + (k * D_ + d) * D_ + e0);
#pragma unroll
      for (int r = 0; r < 2; ++r) {
        const float4 si = *(const float4*)(&S[r][0][k][e0]);
        const float4 so = *(const float4*)(&S[r][1][k][e0]);
        acc_in[r]  += mi.x * si.x + mi.y * si.y + mi.z * si.z + mi.w * si.w;
        acc_out[r] += mo.x * so.x + mo.y * so.y + mo.z * so.z + mo.w * so.w;
      }
    }
  }
#pragma unroll
  for (int r = 0; r < 2; ++r) {
    out[(b * N_ + i0 + r) * (2 * D_) + d]      = acc_in[r];
    out[(b * N_ + i0 + r) * (2 * D_) + D_ + d] = acc_out[r];
  }
}

extern "C" void kernel_launch(void* const* d_in, const int* in_sizes, int n_in,
                              void* d_out, int out_size, void* d_ws, size_t ws_size,
                              hipStream_t stream) {
  const float* h    = (const float*)d_in[0];
  const int*   adj  = (const int*)d_in[1];
  const float* Min  = (const float*)d_in[3];
  const float* Mout = (const float*)d_in[4];
  const float* bias = (const float*)d_in[5];
  float* out = (float*)d_out;

  if (ws_size < WSU_BYTES + 2 * T_BYTES) {
    hipLaunchKernelGGL(ggnn_fallback, dim3(B_ * N_ / 2), dim3(64), 0, stream,
                       h, adj, Min, Mout, bias, out);
    return;
  }
  unsigned short* wsu = (unsigned short*)d_ws;
  __hip_bfloat16* Tin  = (__hip_bfloat16*)((char*)d_ws + WSU_BYTES);
  __hip_bfloat16* Tout = (__hip_bfloat16*)((char*)d_ws + WSU_BYTES + T_BYTES);

  hipLaunchKernelGGL(prep_adj,   dim3(1024), dim3(256), 0, stream, adj, wsu);
  hipLaunchKernelGGL(build_T,    dim3(1024), dim3(256), 0, stream, h, Min, Mout, Tin, Tout);
  hipLaunchKernelGGL(gather_msg, dim3(1024), dim3(256), 0, stream, wsu, Tin, Tout, bias, out);
}

// Round 5
// 158.412 us; speedup vs baseline: 2.6127x; 1.4437x over previous
//
#include <hip/hip_runtime.h>

#define B_ 16
#define N_ 512
#define D_ 64
#define K_ 8

// ---------------- ws layout ----------------
// wsu : [B][N][N] ushort {kin | kout<<8}        8,388,608 B
// Tin : [B][N][K+1][D] bf16                     9,437,184 B
// Tout: [B][N][K+1][D] bf16                     9,437,184 B
// hbf : [B][N][D] bf16                          1,048,576 B
// Mbf : [2][K][D][D] bf16 (rows = kd, 64 e)       131,072 B
#define WSU_BYTES ((size_t)B_ * N_ * N_ * 2)
#define T_BYTES   ((size_t)B_ * N_ * (K_ + 1) * D_ * 2)
#define HBF_BYTES ((size_t)B_ * N_ * D_ * 2)
#define MBF_BYTES ((size_t)2 * K_ * D_ * D_ * 2)
#define TROWB 1152  // (K+1)*D*2 bytes per j row

typedef __attribute__((ext_vector_type(8))) short bf8_t;   // 8 bf16 (4 VGPRs)
typedef __attribute__((ext_vector_type(4))) float f4_t;    // 4 fp32 acc

__device__ __forceinline__ unsigned short f2bf(float x) {  // RNE f32->bf16
  union { float f; unsigned u; } c; c.f = x;
  unsigned r = c.u + 0x7FFFu + ((c.u >> 16) & 1u);
  return (unsigned short)(r >> 16);
}

// ---------- kernel 0: bf16 conversions + zero T slot 0 ----------
__global__ __launch_bounds__(256) void conv_inputs(
    const float* __restrict__ h, const float* __restrict__ Min,
    const float* __restrict__ Mout,
    unsigned short* __restrict__ hbf, unsigned short* __restrict__ Mbf,
    unsigned short* __restrict__ Tin, unsigned short* __restrict__ Tout) {
  const int g = blockIdx.x * 256 + threadIdx.x;   // grid 512 -> 131072 threads
  {  // h: 131072 float4 groups
    const float4 v = ((const float4*)h)[g];
    ushort4 o; o.x = f2bf(v.x); o.y = f2bf(v.y); o.z = f2bf(v.z); o.w = f2bf(v.w);
    ((ushort4*)hbf)[g] = o;
  }
  if (g < 8192) {        // Min: 8192 float4 groups
    const float4 v = ((const float4*)Min)[g];
    ushort4 o; o.x = f2bf(v.x); o.y = f2bf(v.y); o.z = f2bf(v.z); o.w = f2bf(v.w);
    ((ushort4*)Mbf)[g] = o;
  } else if (g < 16384) {  // Mout
    const int t = g - 8192;
    const float4 v = ((const float4*)Mout)[t];
    ushort4 o; o.x = f2bf(v.x); o.y = f2bf(v.y); o.z = f2bf(v.z); o.w = f2bf(v.w);
    ((ushort4*)Mbf)[8192 + t] = o;
  }
  {  // zero slot k=0: 8192 rows x 16 ushort4 chunks = 131072 chunks
    const int row = g >> 4, part = g & 15;
    const ushort4 z = make_ushort4(0, 0, 0, 0);
    ((ushort4*)(Tin  + (size_t)row * 576))[part] = z;
    ((ushort4*)(Tout + (size_t)row * 576))[part] = z;
  }
}

// ---------- kernel A: transpose + pack edge types (ushort per edge) ----------
__global__ __launch_bounds__(256) void prep_adj(const int* __restrict__ adj,
                                                unsigned short* __restrict__ wsu) {
  __shared__ int ta[64][65];
  __shared__ int tb[64][65];
  const int blk = blockIdx.x;          // 1024
  const int xcd = blk & 7, rest = blk >> 3;
  const int b = xcd + 8 * (rest & 1);  // batch b -> XCD b%8
  const int tile = rest >> 1;          // 0..63
  const int i0 = (tile >> 3) * 64, j0 = (tile & 7) * 64;
  const int lane = threadIdx.x & 63, w = threadIdx.x >> 6;
  const int* ab = adj + (size_t)b * N_ * N_;
#pragma unroll
  for (int r = w; r < 64; r += 4) {
    ta[r][lane] = ab[(size_t)(i0 + r) * N_ + j0 + lane];
    tb[r][lane] = ab[(size_t)(j0 + r) * N_ + i0 + lane];
  }
  __syncthreads();
  unsigned short* wb = wsu + (size_t)b * N_ * N_;
#pragma unroll
  for (int r = w; r < 64; r += 4) {
    wb[(size_t)(i0 + r) * N_ + j0 + lane] =
        (unsigned short)(ta[r][lane] | (tb[lane][r] << 8));
  }
}

// ---------- kernel B: T = h x M'^T via MFMA (bf16), slots 1..8 ----------
// C[j, kd] = sum_e A[j,e] * B[e,kd];  B^T[kd,e] = Mbf row kd.
// A-frag: lane needs A[row=l&15, e=8*(l>>4)+0..7]  -> 16B of hbf row
// B-frag: lane needs B[e=8*(l>>4)+0..7, col=l&15]  -> 16B of Mbf row
// D-frag: lane holds D[(l>>4)*4+r, l&15], r=0..3   (m89-verified)
__global__ __launch_bounds__(256) void build_T_mfma(
    const unsigned short* __restrict__ hbf,   // [B][N][64]
    const unsigned short* __restrict__ Mbf,   // [1024][64]
    unsigned short* __restrict__ Tin,
    unsigned short* __restrict__ Tout) {
  const int blk = blockIdx.x;               // 1024
  const int b   = (blk & 7) + 8 * ((blk >> 3) & 1);
  const int u   = blk >> 4;                 // 0..63
  const int jt  = u & 15;                   // 16 j-tiles of 32
  const int kdt = u >> 4;                   // 4 kd-tiles of 256
  const int w = threadIdx.x >> 6, l = threadIdx.x & 63;
  const int j0  = jt * 32;
  const int kd0 = kdt * 256 + w * 64;       // wave's 64 kd (single dir)
  const int r16 = l & 15, grp = l >> 4;

  const unsigned short* ha = hbf + ((size_t)b * N_ + j0 + r16) * 64 + grp * 8;
  bf8_t afr[2][2];
#pragma unroll
  for (int fr = 0; fr < 2; ++fr)
#pragma unroll
    for (int ks = 0; ks < 2; ++ks)
      afr[fr][ks] = *(const bf8_t*)(ha + fr * 16 * 64 + ks * 32);

  const unsigned short* mb = Mbf + (size_t)(kd0 + r16) * 64 + grp * 8;
  bf8_t bfr[4][2];
#pragma unroll
  for (int fc = 0; fc < 4; ++fc)
#pragma unroll
    for (int ks = 0; ks < 2; ++ks)
      bfr[fc][ks] = *(const bf8_t*)(mb + fc * 16 * 64 + ks * 32);

  f4_t acc[2][4];
#pragma unroll
  for (int fr = 0; fr < 2; ++fr)
#pragma unroll
    for (int fc = 0; fc < 4; ++fc) acc[fr][fc] = (f4_t)(0.f);

#pragma unroll
  for (int fr = 0; fr < 2; ++fr)
#pragma unroll
    for (int fc = 0; fc < 4; ++fc) {
      acc[fr][fc] = __builtin_amdgcn_mfma_f32_16x16x32_bf16(
          afr[fr][0], bfr[fc][0], acc[fr][fc], 0, 0, 0);
      acc[fr][fc] = __builtin_amdgcn_mfma_f32_16x16x32_bf16(
          afr[fr][1], bfr[fc][1], acc[fr][fc], 0, 0, 0);
    }

  unsigned short* Tbase = (kd0 >= 512) ? Tout : Tin;
  const int kdl0 = kd0 & 511;
  unsigned short* trow = Tbase + (size_t)b * N_ * 576 + 64;  // slot k+1 = 64+kd
#pragma unroll
  for (int fr = 0; fr < 2; ++fr)
#pragma unroll
    for (int fc = 0; fc < 4; ++fc) {
      const int kd = kdl0 + fc * 16 + r16;
#pragma unroll
      for (int r = 0; r < 4; ++r) {
        const int j = j0 + fr * 16 + grp * 4 + r;
        trow[(size_t)j * 576 + kd] = f2bf(acc[fr][fc][r]);
      }
    }
}

// ---------- kernel C: branch-free edge gather (16 rows/block for L1 reuse) ----------
__global__ __launch_bounds__(512) void gather_msg(
    const unsigned short* __restrict__ wsu,
    const unsigned short* __restrict__ Tin,
    const unsigned short* __restrict__ Tout,
    const float* __restrict__ bias,
    float* __restrict__ out) {
  __shared__ int4 ed4[1024];           // 16 rows x 1KB = 16 KB
  const int blk = blockIdx.x;          // 512
  const int b  = (blk & 7) + 8 * ((blk >> 3) & 1);
  const int i0 = (blk >> 4) * 16;      // 16 rows per block
  const int tid = threadIdx.x;
  const int w = tid >> 6, lane = tid & 63;
  const int half = lane >> 5, lane5 = lane & 31;

  const int4* src = (const int4*)(wsu + ((size_t)b * N_ + i0) * N_);
  ed4[tid]       = src[tid];
  ed4[tid + 512] = src[tid + 512];
  __syncthreads();

  const unsigned short* edrow =
      (const unsigned short*)ed4 + (2 * w + half) * N_;  // this lane's row

  const char* tinb  = (const char*)Tin  + (size_t)b * N_ * TROWB;
  const char* toutb = (const char*)Tout + (size_t)b * N_ * TROWB;
  unsigned voff = (unsigned)lane5 * 4;   // byte offset of d-pair in 128B k-row
  float aI0 = 0.f, aI1 = 0.f, aO0 = 0.f, aO1 = 0.f;
#pragma unroll 8
  for (int j = 0; j < N_; ++j) {
    const unsigned v = edrow[j];
    const unsigned ui = *(const unsigned*)(tinb  + (voff + ((v & 0xFFu) << 7)));
    const unsigned uo = *(const unsigned*)(toutb + (voff + ((v >> 8) << 7)));
    aI0 += __uint_as_float(ui << 16);
    aI1 += __uint_as_float(ui & 0xFFFF0000u);
    aO0 += __uint_as_float(uo << 16);
    aO1 += __uint_as_float(uo & 0xFFFF0000u);
    voff += TROWB;
  }

  const int row = i0 + 2 * w + half;
  const int d = lane5 * 2;
  float* orow = out + ((size_t)b * N_ + row) * (2 * D_);
  const float2 bi = *(const float2*)(bias + d);
  const float2 bo = *(const float2*)(bias + D_ + d);
  *(float2*)(orow + d)      = make_float2(aI0 + bi.x, aI1 + bi.y);
  *(float2*)(orow + D_ + d) = make_float2(aO0 + bo.x, aO1 + bo.y);
}

// ---------- fallback (branch-tree kernel) if ws is too small ----------
#define ACCUM(kv, bucket) switch (kv) { \
    case 1: (bucket)[0] += v_; break; case 2: (bucket)[1] += v_; break; \
    case 3: (bucket)[2] += v_; break; case 4: (bucket)[3] += v_; break; \
    case 5: (bucket)[4] += v_; break; case 6: (bucket)[5] += v_; break; \
    case 7: (bucket)[6] += v_; break; case 8: (bucket)[7] += v_; break; \
    default: break; }

__global__ __launch_bounds__(64) void ggnn_fallback(
    const float* __restrict__ h, const int* __restrict__ adj,
    const float* __restrict__ Min, const float* __restrict__ Mout,
    const float* __restrict__ bias, float* __restrict__ out) {
  const int blk = blockIdx.x;
  const int b  = blk / (N_ / 2);
  const int i0 = (blk % (N_ / 2)) * 2;
  const int d  = threadIdx.x;
  float s_in[2][K_], s_out[2][K_];
#pragma unroll
  for (int r = 0; r < 2; ++r)
#pragma unroll
    for (int k = 0; k < K_; ++k) { s_in[r][k] = 0.f; s_out[r][k] = 0.f; }
  const int* rowp0 = adj + (b * N_ + i0) * N_;
  const int* rowp1 = rowp0 + N_;
  const int* colp  = adj + b * N_ * N_ + i0;
  const float* hb  = h + b * N_ * D_ + d;
  for (int j0 = 0; j0 < N_; j0 += 8) {
    float hv[8]; int kr0[8], kr1[8], kc0[8], kc1[8];
#pragma unroll
    for (int m = 0; m < 8; ++m) {
      hv[m] = hb[(j0 + m) * D_];
      kr0[m] = rowp0[j0 + m]; kr1[m] = rowp1[j0 + m];
      kc0[m] = colp[(j0 + m) * N_]; kc1[m] = colp[(j0 + m) * N_ + 1];
    }
#pragma unroll
    for (int m = 0; m < 8; ++m) {
      const float v_ = hv[m];
      ACCUM(kr0[m], s_in[0]); ACCUM(kr1[m], s_in[1]);
      ACCUM(kc0[m], s_out[0]); ACCUM(kc1[m], s_out[1]);
    }
  }
  __shared__ float S[2][2][K_][D_];
#pragma unroll
  for (int r = 0; r < 2; ++r)
#pragma unroll
    for (int k = 0; k < K_; ++k) { S[r][0][k][d] = s_in[r][k]; S[r][1][k][d] = s_out[r][k]; }
  __syncthreads();
  float acc_in[2], acc_out[2];
#pragma unroll
  for (int r = 0; r < 2; ++r) { acc_in[r] = bias[d]; acc_out[r] = bias[D_ + d]; }
  for (int k = 0; k < K_; ++k) {
#pragma unroll
    for (int e0 = 0; e0 < D_; e0 += 4) {
      const float4 mi = *(const float4*)(Min  + (k * D_ + d) * D_ + e0);
      const float4 mo = *(const float4*)(Mout + (k * D_ + d) * D_ + e0);
#pragma unroll
      for (int r = 0; r < 2; ++r) {
        const float4 si = *(const float4*)(&S[r][0][k][e0]);
        const float4 so = *(const float4*)(&S[r][1][k][e0]);
        acc_in[r]  += mi.x * si.x + mi.y * si.y + mi.z * si.z + mi.w * si.w;
        acc_out[r] += mo.x * so.x + mo.y * so.y + mo.z * so.z + mo.w * so.w;
      }
    }
  }
#pragma unroll
  for (int r = 0; r < 2; ++r) {
    out[(b * N_ + i0 + r) * (2 * D_) + d]      = acc_in[r];
    out[(b * N_ + i0 + r) * (2 * D_) + D_ + d] = acc_out[r];
  }
}

extern "C" void kernel_launch(void* const* d_in, const int* in_sizes, int n_in,
                              void* d_out, int out_size, void* d_ws, size_t ws_size,
                              hipStream_t stream) {
  const float* h    = (const float*)d_in[0];
  const int*   adj  = (const int*)d_in[1];
  const float* Min  = (const float*)d_in[3];
  const float* Mout = (const float*)d_in[4];
  const float* bias = (const float*)d_in[5];
  float* out = (float*)d_out;

  if (ws_size < WSU_BYTES + 2 * T_BYTES + HBF_BYTES + MBF_BYTES) {
    hipLaunchKernelGGL(ggnn_fallback, dim3(B_ * N_ / 2), dim3(64), 0, stream,
                       h, adj, Min, Mout, bias, out);
    return;
  }
  unsigned short* wsu  = (unsigned short*)d_ws;
  unsigned short* Tin  = (unsigned short*)((char*)d_ws + WSU_BYTES);
  unsigned short* Tout = (unsigned short*)((char*)d_ws + WSU_BYTES + T_BYTES);
  unsigned short* hbf  = (unsigned short*)((char*)d_ws + WSU_BYTES + 2 * T_BYTES);
  unsigned short* Mbf  = (unsigned short*)((char*)d_ws + WSU_BYTES + 2 * T_BYTES + HBF_BYTES);

  hipLaunchKernelGGL(conv_inputs,  dim3(512),  dim3(256), 0, stream,
                     h, Min, Mout, hbf, Mbf, Tin, Tout);
  hipLaunchKernelGGL(prep_adj,     dim3(1024), dim3(256), 0, stream, adj, wsu);
  hipLaunchKernelGGL(build_T_mfma, dim3(1024), dim3(256), 0, stream, hbf, Mbf, Tin, Tout);
  hipLaunchKernelGGL(gather_msg,   dim3(512),  dim3(512), 0, stream,
                     wsu, Tin, Tout, bias, out);
}